// Round 5
// baseline (600.777 us; speedup 1.0000x reference)
//
#include <hip/hip_runtime.h>
#include <hip/hip_bf16.h>

typedef __hip_bfloat16 bf16;
typedef __attribute__((ext_vector_type(8))) __bf16 bf16x8;
typedef __attribute__((ext_vector_type(4))) float  f32x4;

#define HW   65536
#define WID  256
#define CC   96
#define NB   4
static const size_t S_ELEMS = (size_t)NB * CC * HW;  // 25,165,824 elements

__device__ __forceinline__ float lo2f(unsigned u) { unsigned x = u << 16;        return __builtin_bit_cast(float, x); }
__device__ __forceinline__ float hi2f(unsigned u) { unsigned x = u & 0xffff0000u; return __builtin_bit_cast(float, x); }
__device__ __forceinline__ unsigned short f2bu(float f) {
    return __builtin_bit_cast(unsigned short, __float2bfloat16(f));
}

// exact-GELU via Abramowitz-Stegun 7.1.26 erf (|err| < 1.5e-7)
__device__ __forceinline__ float gelu_erf(float v) {
    float z  = fabsf(v) * 0.70710678118654752f;
    float t  = __builtin_amdgcn_rcpf(1.f + 0.3275911f * z);
    float poly = t * (0.254829592f + t * (-0.284496736f + t * (1.421413741f
               + t * (-1.453152027f + t * 1.061405429f))));
    float erfz = 1.f - poly * __expf(-z * z);
    float erfv = copysignf(erfz, v);
    return 0.5f * v * (1.f + erfv);
}

// ---------------- Kernel 1: LayerNorm over channel dim of NCHW ----------------
__global__ __launch_bounds__(256) void ln_kernel(
    const float* __restrict__ x, const float* __restrict__ lw,
    const float* __restrict__ lb, bf16* __restrict__ y)
{
    int t  = blockIdx.x * 256 + threadIdx.x;   // [0, 131072)
    int b  = t >> 15;
    int hw = (t & 32767) * 2;
    size_t base = (size_t)b * CC * HW + hw;

    float s0 = 0.f, s1 = 0.f, q0 = 0.f, q1 = 0.f;
    for (int c = 0; c < CC; ++c) {
        float2 v = *reinterpret_cast<const float2*>(&x[base + (size_t)c * HW]);
        s0 += v.x; s1 += v.y; q0 += v.x * v.x; q1 += v.y * v.y;
    }
    float mu0 = s0 * (1.f / 96.f), mu1 = s1 * (1.f / 96.f);
    float rs0 = rsqrtf(q0 * (1.f / 96.f) - mu0 * mu0 + 1e-6f);
    float rs1 = rsqrtf(q1 * (1.f / 96.f) - mu1 * mu1 + 1e-6f);

    for (int c = 0; c < CC; ++c) {
        float2 v = *reinterpret_cast<const float2*>(&x[base + (size_t)c * HW]);
        float g = lw[c], be = lb[c];
        bf16 o[2];
        o[0] = __float2bfloat16((v.x - mu0) * rs0 * g + be);
        o[1] = __float2bfloat16((v.y - mu1) * rs1 * g + be);
        *reinterpret_cast<uint*>(&y[base + (size_t)c * HW]) = *reinterpret_cast<uint*>(o);
    }
}

// ---------------- conv1x1 via MFMA 16x16x32 bf16, multi-tile + prefetch ------
// Block = 4 waves, stages weights ONCE, then loops over TILES position-tiles
// (128 positions each). Per ks-split: write prefetched X regs -> LDS, barrier,
// issue next tile's global loads (latency hides under MFMA phase), MFMA,
// barrier. X stage writes are channel-pair-packed u32 (2-way banks = free).
// Grid = 2048/TILES = 512 -> exactly 2 blocks/CU, perfectly balanced.
__device__ __forceinline__ int swzo(int row, int col, int width) {
    return (row * width + col) ^ ((((row & 7) ^ ((row >> 3) & 7)) << 3));
}

#define CONV_TILES 4
#define CONV_GRID  512

template <typename TI, typename TOT, int CIN, int COUT, bool GELU, bool HASRES>
__global__ __launch_bounds__(256, 2) void conv1x1_mfma(
    const TI* __restrict__ in, const float* __restrict__ wgt,
    const float* __restrict__ bias, const float* __restrict__ resid,
    TOT* __restrict__ out)
{
    constexpr int MT     = COUT / 16;
    constexpr int KSPLIT = CIN / 96;         // 1 (CIN=96) or 2 (CIN=192)
    constexpr int CS     = 96;               // staged channels per split
    static_assert(CIN == KSPLIT * CS, "CIN must be 96 or 192");

    __shared__ unsigned short s_w[COUT * CIN];
    __shared__ unsigned short s_x[128 * CS];
    __shared__ float          s_b[COUT];

    const int tid  = threadIdx.x;
    const int lane = tid & 63;
    const int wave = tid >> 6;
    const int q    = lane >> 4;
    const int n    = lane & 15;

    // ---- stage weights fp32 -> bf16 LDS (swizzled), + bias  [once per block]
    constexpr int C4 = CIN / 4;
    for (int k = tid; k < COUT * C4; k += 256) {
        int o = k / C4, c4 = (k - o * C4) * 4;
        float4 w4 = *reinterpret_cast<const float4*>(&wgt[o * CIN + c4]);
        ushort4 pk = make_ushort4(f2bu(w4.x), f2bu(w4.y), f2bu(w4.z), f2bu(w4.w));
        *reinterpret_cast<ushort4*>(&s_w[swzo(o, c4, CIN)]) = pk;
    }
    for (int k = tid; k < COUT; k += 256) s_b[k] = bias[k];

    // ---- prefetch registers: 3 items = (chan-pair cp, pos-block pb)
    uint4  pfa[3], pfb[3];                       // bf16 input path
    float4 qa0[3], qa1[3], qb0[3], qb1[3];       // fp32 input path

    auto issue_pf = [&](int tg, int ks) {
        const int pos0 = tg * 128;
        const int bb   = pos0 >> 16;
        const int hw0  = pos0 & 65535;
        const TI* inb  = in + (size_t)bb * CIN * HW;
#pragma unroll
        for (int k = 0; k < 3; ++k) {
            const int idx = tid + k * 256;
            const int cp = idx >> 4, pb = idx & 15;
            const TI* gp = inb + (size_t)(ks * CS + 2 * cp) * HW + hw0 + pb * 8;
            if constexpr (__is_same(TI, float)) {
                qa0[k] = *reinterpret_cast<const float4*>(gp);
                qa1[k] = *reinterpret_cast<const float4*>(gp + 4);
                qb0[k] = *reinterpret_cast<const float4*>(gp + HW);
                qb1[k] = *reinterpret_cast<const float4*>(gp + HW + 4);
            } else {
                pfa[k] = *reinterpret_cast<const uint4*>(gp);
                pfb[k] = *reinterpret_cast<const uint4*>(gp + HW);
            }
        }
    };
    auto write_pf = [&]() {
#pragma unroll
        for (int k = 0; k < 3; ++k) {
            const int idx = tid + k * 256;
            const int cp = idx >> 4, pb = idx & 15;
            unsigned short ua[8], ub[8];
            if constexpr (__is_same(TI, float)) {
                float fa[8] = {qa0[k].x, qa0[k].y, qa0[k].z, qa0[k].w,
                               qa1[k].x, qa1[k].y, qa1[k].z, qa1[k].w};
                float fb[8] = {qb0[k].x, qb0[k].y, qb0[k].z, qb0[k].w,
                               qb1[k].x, qb1[k].y, qb1[k].z, qb1[k].w};
#pragma unroll
                for (int i = 0; i < 8; ++i) { ua[i] = f2bu(fa[i]); ub[i] = f2bu(fb[i]); }
            } else {
                *reinterpret_cast<uint4*>(ua) = pfa[k];
                *reinterpret_cast<uint4*>(ub) = pfb[k];
            }
#pragma unroll
            for (int i = 0; i < 8; ++i) {
                uint d = (uint)ua[i] | ((uint)ub[i] << 16);
                *reinterpret_cast<uint*>(&s_x[swzo(pb * 8 + i, 2 * cp, CS)]) = d;
            }
        }
    };

    const int pl0 = wave * 32 + n;   // tile-local position for bf0
    const int pl1 = pl0 + 16;        // tile-local position for bf1

    issue_pf(blockIdx.x * CONV_TILES, 0);
    __syncthreads();                 // weights staged (drains first prefetch too)

    for (int t = 0; t < CONV_TILES; ++t) {
        const int tg   = blockIdx.x * CONV_TILES + t;
        const int pos0 = tg * 128;
        const int b    = pos0 >> 16;
        const int hw0  = pos0 & 65535;

        f32x4 acc[MT][2];
#pragma unroll
        for (int mt = 0; mt < MT; ++mt) {
            acc[mt][0] = {0.f, 0.f, 0.f, 0.f};
            acc[mt][1] = {0.f, 0.f, 0.f, 0.f};
        }

#pragma unroll
        for (int ks = 0; ks < KSPLIT; ++ks) {
            write_pf();              // regs (t,ks) -> s_x
            __syncthreads();         // s_x ready
            // issue next stage's loads; latency hides under MFMA below
            if (ks + 1 < KSPLIT)            issue_pf(tg, ks + 1);
            else if (t + 1 < CONV_TILES)    issue_pf(tg + 1, 0);

#pragma unroll
            for (int kt = 0; kt < CS / 32; ++kt) {
                const int col = kt * 32 + q * 8;
                union { unsigned short u[8]; bf16x8 v; } bf0, bf1;
                *reinterpret_cast<uint4*>(bf0.u) =
                    *reinterpret_cast<const uint4*>(&s_x[swzo(pl0, col, CS)]);
                *reinterpret_cast<uint4*>(bf1.u) =
                    *reinterpret_cast<const uint4*>(&s_x[swzo(pl1, col, CS)]);
#pragma unroll
                for (int mt = 0; mt < MT; ++mt) {
                    union { unsigned short u[8]; bf16x8 v; } fa;
                    *reinterpret_cast<uint4*>(fa.u) =
                        *reinterpret_cast<const uint4*>(&s_w[swzo(mt * 16 + n, ks * CS + col, CIN)]);
                    acc[mt][0] = __builtin_amdgcn_mfma_f32_16x16x32_bf16(fa.v, bf0.v, acc[mt][0], 0, 0, 0);
                    acc[mt][1] = __builtin_amdgcn_mfma_f32_16x16x32_bf16(fa.v, bf1.v, acc[mt][1], 0, 0, 0);
                }
            }
            if (ks + 1 < KSPLIT || t + 1 < CONV_TILES)
                __syncthreads();     // all MFMA reads done before next overwrite
        }

        // ---- epilogue for tile t
        const int p0 = hw0 + pl0;
        const int p1 = hw0 + pl1;
        const size_t obase = (size_t)b * COUT * HW;
#pragma unroll
        for (int mt = 0; mt < MT; ++mt) {
#pragma unroll
            for (int nt = 0; nt < 2; ++nt) {
                const int p = (nt == 0) ? p0 : p1;
#pragma unroll
                for (int r = 0; r < 4; ++r) {
                    const int o = mt * 16 + q * 4 + r;
                    float v = acc[mt][nt][r] + s_b[o];
                    if constexpr (GELU) v = gelu_erf(v);
                    const size_t idx = obase + (size_t)o * HW + p;
                    if constexpr (HASRES) v += resid[idx];
                    if constexpr (__is_same(TOT, float)) out[idx] = v;
                    else                                 out[idx] = __float2bfloat16(v);
                }
            }
        }
    }
}

// ---------------- Kernel 3: experts, TRANSPOSED LDS stencil ----------------
// Layout: reads conflict-free (11w / 5w mod 32 bijective per half-wave);
// stage writes row-pair u32-packed, lane-mapped conflict-free (round 4).
#define XR     20
#define XPITCH 22      // 11 dwords (odd)
#define TPITCH 10      // 5 dwords (odd)
#define XCOLS  268
#define TCOLS  258

__global__ __launch_bounds__(256) void experts_kernel(
    const bf16* __restrict__ xn, const bf16* __restrict__ t0,
    const float* __restrict__ w0, const float* __restrict__ b0,
    const float* __restrict__ w1, const float* __restrict__ b1,
    const float* __restrict__ w2, const float* __restrict__ b2,
    const float* __restrict__ sw, const float* __restrict__ prompt,
    bf16* __restrict__ xa)
{
    __shared__ alignas(16) unsigned short sxT[XCOLS * XPITCH];
    __shared__ alignas(16) unsigned short stT[TCOLS * TPITCH];

    const int tid  = threadIdx.x;
    const int lane = tid & 63;
    const int wave = tid >> 6;
    const int bid = blockIdx.x;
    const int h0  = (bid & 31) * 8;
    const int bc  = bid >> 5;
    const int b   = bc / 96;
    const int c   = bc - b * 96;
    const size_t pbase = (size_t)bc * HW;

    const bf16* xp = xn + pbase;
    const bf16* tp = t0 + pbase;
    uint* sx32 = reinterpret_cast<uint*>(sxT);
    uint* st32 = reinterpret_cast<uint*>(stT);

    // ---- edge-pad zero fill (cols 0..5 & 262..267 of X; cols 0 & 257 of T)
    if (tid < 132) {                       // 12 cols x 11 dwords
        int cc = tid / 11, d = tid - cc * 11;
        int col = (cc < 6) ? cc : 256 + cc;
        sx32[col * 11 + d] = 0u;
    } else if (tid < 142) {                // 2 cols x 5 dwords
        int i = tid - 132;
        int col = (i < 5) ? 0 : 257;
        int d   = (i < 5) ? i : i - 5;
        st32[col * 5 + d] = 0u;
    }

    // ---- stage X: item = (rowpair rp, chunk ch); packed u32 writes
    {
        const int rp = (lane >> 2) & 7;
        const int ch = 8 * wave + (lane & 3) + ((lane >> 5) << 2);
        const int gh0 = h0 - 6 + 2 * rp, gh1 = gh0 + 1;
        union { uint4 q; unsigned short u[8]; } a, bb;
        a.q  = ((unsigned)gh0 < 256u) ? *reinterpret_cast<const uint4*>(xp + gh0 * WID + ch * 8)
                                      : make_uint4(0u, 0u, 0u, 0u);
        bb.q = ((unsigned)gh1 < 256u) ? *reinterpret_cast<const uint4*>(xp + gh1 * WID + ch * 8)
                                      : make_uint4(0u, 0u, 0u, 0u);
        const int base = 11 * (6 + 8 * ch) + rp;
#pragma unroll
        for (int j = 0; j < 8; ++j)
            sx32[base + 11 * j] = (uint)a.u[j] | ((uint)bb.u[j] << 16);
    }
    if (wave == 2) {   // X tail: rp 8..9
        const int rp = 8 + ((lane >> 2) & 1);
        const int ch = (lane & 3) + (((lane >> 3) & 7) << 2);
        const int gh0 = h0 - 6 + 2 * rp, gh1 = gh0 + 1;
        union { uint4 q; unsigned short u[8]; } a, bb;
        a.q  = ((unsigned)gh0 < 256u) ? *reinterpret_cast<const uint4*>(xp + gh0 * WID + ch * 8)
                                      : make_uint4(0u, 0u, 0u, 0u);
        bb.q = ((unsigned)gh1 < 256u) ? *reinterpret_cast<const uint4*>(xp + gh1 * WID + ch * 8)
                                      : make_uint4(0u, 0u, 0u, 0u);
        const int base = 11 * (6 + 8 * ch) + rp;
#pragma unroll
        for (int j = 0; j < 8; ++j)
            sx32[base + 11 * j] = (uint)a.u[j] | ((uint)bb.u[j] << 16);
    }
    if (wave < 2) {    // T main: rp 0..3
        const int rp = (lane >> 3) & 3;
        const int ch = 16 * wave + (lane & 7) + ((lane >> 5) << 3);
        const int gh0 = h0 - 1 + 2 * rp, gh1 = gh0 + 1;
        union { uint4 q; unsigned short u[8]; } a, bb;
        a.q  = ((unsigned)gh0 < 256u) ? *reinterpret_cast<const uint4*>(tp + gh0 * WID + ch * 8)
                                      : make_uint4(0u, 0u, 0u, 0u);
        bb.q = ((unsigned)gh1 < 256u) ? *reinterpret_cast<const uint4*>(tp + gh1 * WID + ch * 8)
                                      : make_uint4(0u, 0u, 0u, 0u);
        const int base = 5 * (1 + 8 * ch) + rp;
#pragma unroll
        for (int j = 0; j < 8; ++j)
            st32[base + 5 * j] = (uint)a.u[j] | ((uint)bb.u[j] << 16);
    }
    if (wave == 3 && lane < 32) {   // T tail: rp 4
        const int rp = 4;
        const int ch = lane;
        const int gh0 = h0 - 1 + 2 * rp, gh1 = gh0 + 1;
        union { uint4 q; unsigned short u[8]; } a, bb;
        a.q  = ((unsigned)gh0 < 256u) ? *reinterpret_cast<const uint4*>(tp + gh0 * WID + ch * 8)
                                      : make_uint4(0u, 0u, 0u, 0u);
        bb.q = ((unsigned)gh1 < 256u) ? *reinterpret_cast<const uint4*>(tp + gh1 * WID + ch * 8)
                                      : make_uint4(0u, 0u, 0u, 0u);
        const int base = 5 * (1 + 8 * ch) + rp;
#pragma unroll
        for (int j = 0; j < 8; ++j)
            st32[base + 5 * j] = (uint)a.u[j] | ((uint)bb.u[j] << 16);
    }

    // ---- per-channel weights (block-uniform -> scalar loads)
    float wk0[9], wk1[9], wk2[25];
#pragma unroll
    for (int i = 0; i < 9; ++i)  wk0[i] = w0[c * 9 + i];
#pragma unroll
    for (int i = 0; i < 9; ++i)  wk1[i] = w1[c * 9 + i];
#pragma unroll
    for (int i = 0; i < 25; ++i) wk2[i] = w2[c * 25 + i];
    const float bb0 = b0[c], bb1 = b1[c], bb2 = b2[c];
    const float s0 = sw[b * 3 + 0], s1 = sw[b * 3 + 1], s2 = sw[b * 3 + 2];
    const float pr = 1.f + prompt[b * 96 + c];

    __syncthreads();

    // ---- compute: thread = column w, 8 vertical outputs
    const int w = tid;
    float acc0[8], acc1[8], acc2[8];
#pragma unroll
    for (int r = 0; r < 8; ++r) { acc0[r] = bb0; acc1[r] = bb1; acc2[r] = bb2; }

    const unsigned short* bx = &sxT[w * XPITCH];  // = LDS col of global col (w-6)
    const unsigned short* bt = &stT[w * TPITCH];  // = LDS col of global col (w-1)

    // e2: 5x5 dil 3; e1 center column folded into kw=2 strip
#pragma unroll
    for (int kw = 0; kw < 5; ++kw) {
        float cv[20];
#pragma unroll
        for (int j = 0; j < 10; ++j) {
            unsigned u = *reinterpret_cast<const unsigned*>(&bx[kw * 3 * XPITCH + 2 * j]);
            cv[2 * j]     = lo2f(u);
            cv[2 * j + 1] = hi2f(u);
        }
#pragma unroll
        for (int kh = 0; kh < 5; ++kh) {
            const float wv = wk2[kh * 5 + kw];
#pragma unroll
            for (int r = 0; r < 8; ++r) acc2[r] += wv * cv[r + 3 * kh];
        }
        if (kw == 2) {
#pragma unroll
            for (int kh = 0; kh < 3; ++kh) {
                const float wv = wk1[kh * 3 + 1];
#pragma unroll
                for (int r = 0; r < 8; ++r) acc1[r] += wv * cv[r + 2 * kh + 4];
            }
        }
    }
    // e1: 3x3 dil 2, kw = 0 and 2
#pragma unroll
    for (int kwh = 0; kwh < 2; ++kwh) {
        const int kw = kwh * 2;
        float cv[12];
#pragma unroll
        for (int j = 0; j < 6; ++j) {
            unsigned u = *reinterpret_cast<const unsigned*>(&bx[(4 + 2 * kw) * XPITCH + 4 + 2 * j]);
            cv[2 * j]     = lo2f(u);
            cv[2 * j + 1] = hi2f(u);
        }
#pragma unroll
        for (int kh = 0; kh < 3; ++kh) {
            const float wv = wk1[kh * 3 + kw];
#pragma unroll
            for (int r = 0; r < 8; ++r) acc1[r] += wv * cv[r + 2 * kh];
        }
    }
    // e0: 3x3 dil 1 on t0
#pragma unroll
    for (int kw = 0; kw < 3; ++kw) {
        float cv[10];
#pragma unroll
        for (int j = 0; j < 5; ++j) {
            unsigned u = *reinterpret_cast<const unsigned*>(&bt[kw * TPITCH + 2 * j]);
            cv[2 * j]     = lo2f(u);
            cv[2 * j + 1] = hi2f(u);
        }
#pragma unroll
        for (int kh = 0; kh < 3; ++kh) {
            const float wv = wk0[kh * 3 + kw];
#pragma unroll
            for (int r = 0; r < 8; ++r) acc0[r] += wv * cv[r + kh];
        }
    }

    // ---- combine + store
    bf16* op = xa + pbase + (size_t)h0 * WID + w;
#pragma unroll
    for (int r = 0; r < 8; ++r) {
        float v = (s0 * acc0[r] + s1 * acc1[r] + s2 * acc2[r]) * pr;
        op[r * WID] = __float2bfloat16(v);
    }
}

// ---------------- launch ----------------
extern "C" void kernel_launch(void* const* d_in, const int* in_sizes, int n_in,
                              void* d_out, int out_size, void* d_ws, size_t ws_size,
                              hipStream_t stream)
{
    const float* x       = (const float*)d_in[0];
    const float* prompt  = (const float*)d_in[1];
    const float* sw      = (const float*)d_in[2];
    const float* ln_w    = (const float*)d_in[3];
    const float* ln_b    = (const float*)d_in[4];
    const float* e0_pw_w = (const float*)d_in[5];
    const float* e0_pw_b = (const float*)d_in[6];
    const float* e0_dw_w = (const float*)d_in[7];
    const float* e0_dw_b = (const float*)d_in[8];
    const float* e1_dw_w = (const float*)d_in[9];
    const float* e1_dw_b = (const float*)d_in[10];
    const float* e2_dw_w = (const float*)d_in[11];
    const float* e2_dw_b = (const float*)d_in[12];
    const float* proj_w  = (const float*)d_in[13];
    const float* proj_b  = (const float*)d_in[14];
    const float* ffn1_w  = (const float*)d_in[15];
    const float* ffn1_b  = (const float*)d_in[16];
    const float* ffn2_w  = (const float*)d_in[17];
    const float* ffn2_b  = (const float*)d_in[18];

    float* out = (float*)d_out;                 // x1 lives here fp32 between k4..k6
    bf16*  ws  = (bf16*)d_ws;
    bf16*  A   = ws;                 // xn  bf16 (48 MB)
    bf16*  Bt  = ws + S_ELEMS;       // t0  bf16 (48 MB)
    bf16*  Cx  = ws + 2 * S_ELEMS;   // xa  bf16 (48 MB)  -> peak ws = 144 MB
    bf16*  E   = ws;                 // h (192 ch) bf16 (96 MB), reuses A+Bt once dead

    // 1) xn = LayerNorm_c(x)
    ln_kernel<<<512, 256, 0, stream>>>(x, ln_w, ln_b, A);
    // 2) t0 = conv1x1(xn, e0_pw)
    conv1x1_mfma<bf16, bf16, 96, 96, false, false>
        <<<CONV_GRID, 256, 0, stream>>>(A, e0_pw_w, e0_pw_b, nullptr, Bt);
    // 3) xa = (s0*dw3(t0) + s1*dw3d2(xn) + s2*dw5d3(xn)) * (1+prompt)
    experts_kernel<<<12288, 256, 0, stream>>>(A, Bt, e0_dw_w, e0_dw_b, e1_dw_w, e1_dw_b,
                                              e2_dw_w, e2_dw_b, sw, prompt, Cx);
    // 4) x1 = x + conv1x1(xa, proj)  -> d_out (fp32)
    conv1x1_mfma<bf16, float, 96, 96, false, true>
        <<<CONV_GRID, 256, 0, stream>>>(Cx, proj_w, proj_b, x, out);
    // 5) h = gelu(conv1x1(x1, ffn1)) -> E (bf16)
    conv1x1_mfma<float, bf16, 96, 192, true, false>
        <<<CONV_GRID, 256, 0, stream>>>(out, ffn1_w, ffn1_b, nullptr, E);
    // 6) out = x1 + conv1x1(h, ffn2) -> d_out (in-place, per-thread same-address RMW)
    conv1x1_mfma<bf16, float, 192, 96, false, true>
        <<<CONV_GRID, 256, 0, stream>>>(E, ffn2_w, ffn2_b, out, out);
}

// Round 6
// 484.669 us; speedup vs baseline: 1.2396x; 1.2396x over previous
//
#include <hip/hip_runtime.h>
#include <hip/hip_bf16.h>

typedef __hip_bfloat16 bf16;
typedef __attribute__((ext_vector_type(8))) __bf16 bf16x8;
typedef __attribute__((ext_vector_type(4))) float  f32x4;

#define HW   65536
#define WID  256
#define CC   96
#define NB   4
static const size_t S_ELEMS = (size_t)NB * CC * HW;  // 25,165,824 elements

__device__ __forceinline__ float lo2f(unsigned u) { unsigned x = u << 16;        return __builtin_bit_cast(float, x); }
__device__ __forceinline__ float hi2f(unsigned u) { unsigned x = u & 0xffff0000u; return __builtin_bit_cast(float, x); }
__device__ __forceinline__ unsigned short f2bu(float f) {
    return __builtin_bit_cast(unsigned short, __float2bfloat16(f));
}

// exact-GELU via Abramowitz-Stegun 7.1.26 erf (|err| < 1.5e-7)
__device__ __forceinline__ float gelu_erf(float v) {
    float z  = fabsf(v) * 0.70710678118654752f;
    float t  = __builtin_amdgcn_rcpf(1.f + 0.3275911f * z);
    float poly = t * (0.254829592f + t * (-0.284496736f + t * (1.421413741f
               + t * (-1.453152027f + t * 1.061405429f))));
    float erfz = 1.f - poly * __expf(-z * z);
    float erfv = copysignf(erfz, v);
    return 0.5f * v * (1.f + erfv);
}

// ---------------- Kernel 1: LayerNorm over channel dim of NCHW ----------------
__global__ __launch_bounds__(256) void ln_kernel(
    const float* __restrict__ x, const float* __restrict__ lw,
    const float* __restrict__ lb, bf16* __restrict__ y)
{
    int t  = blockIdx.x * 256 + threadIdx.x;   // [0, 131072)
    int b  = t >> 15;
    int hw = (t & 32767) * 2;
    size_t base = (size_t)b * CC * HW + hw;

    float s0 = 0.f, s1 = 0.f, q0 = 0.f, q1 = 0.f;
    for (int c = 0; c < CC; ++c) {
        float2 v = *reinterpret_cast<const float2*>(&x[base + (size_t)c * HW]);
        s0 += v.x; s1 += v.y; q0 += v.x * v.x; q1 += v.y * v.y;
    }
    float mu0 = s0 * (1.f / 96.f), mu1 = s1 * (1.f / 96.f);
    float rs0 = rsqrtf(q0 * (1.f / 96.f) - mu0 * mu0 + 1e-6f);
    float rs1 = rsqrtf(q1 * (1.f / 96.f) - mu1 * mu1 + 1e-6f);

    for (int c = 0; c < CC; ++c) {
        float2 v = *reinterpret_cast<const float2*>(&x[base + (size_t)c * HW]);
        float g = lw[c], be = lb[c];
        bf16 o[2];
        o[0] = __float2bfloat16((v.x - mu0) * rs0 * g + be);
        o[1] = __float2bfloat16((v.y - mu1) * rs1 * g + be);
        *reinterpret_cast<uint*>(&y[base + (size_t)c * HW]) = *reinterpret_cast<uint*>(o);
    }
}

// ---------------- conv1x1 via MFMA 16x16x32 bf16, slice-staged weights -------
// GEMM: out[o][p] = sum_c W[o][c] * X[c][p].  Block = 4 waves, 128 positions.
// LDS capped at ~43 KB -> 3 blocks/CU (round-4's 62 KB gave only 2):
//   s_w: ONE 96x96 weight slice (18 KB), looped over {K-slices} x {out-slices}
//   s_x: one 96-channel X slice [pos][chan] (24 KB), swizzled; staged once per
//        K-slice (reused across out-slices when CIN==96)
// X stage writes channel-pair-packed u32 (enumerated: 32 banks, 2-way = free).
// Grid 2048 (single tile per block) -- identical global access order to the
// proven round-4 schedule (FETCH must stay L3-friendly; round-5 lesson).
__device__ __forceinline__ int swzo(int row, int col, int width) {
    return (row * width + col) ^ ((((row & 7) ^ ((row >> 3) & 7)) << 3));
}

template <typename TI, typename TOT, int CIN, int COUT, bool GELU, bool HASRES>
__global__ __launch_bounds__(256) void conv1x1_mfma(
    const TI* __restrict__ in, const float* __restrict__ wgt,
    const float* __restrict__ bias, const float* __restrict__ resid,
    TOT* __restrict__ out)
{
    constexpr int KSPLIT = CIN / 96;     // 1 (CIN=96) or 2 (CIN=192)
    constexpr int OSPLIT = COUT / 96;    // 1 (COUT=96) or 2 (COUT=192)
    constexpr int MT     = 6;            // 96/16 output tiles per slice
    static_assert(CIN == KSPLIT * 96 && COUT == OSPLIT * 96, "96-multiples only");

    __shared__ unsigned short s_w[96 * 96];    // 18 KB: one (os,ks) weight slice
    __shared__ unsigned short s_x[128 * 96];   // 24 KB: one ks X slice
    __shared__ float          s_b[COUT];

    const int tid  = threadIdx.x;
    const int lane = tid & 63;
    const int wave = tid >> 6;
    const int q    = lane >> 4;
    const int n    = lane & 15;

    const int pos0 = blockIdx.x * 128;
    const int b    = pos0 >> 16;
    const int hw0  = pos0 & 65535;

    for (int k = tid; k < COUT; k += 256) s_b[k] = bias[k];

    const TI* inb = in + (size_t)b * CIN * HW;
    const int pl0 = wave * 32 + n;   // tile-local position for bf0
    const int pl1 = pl0 + 16;        // tile-local position for bf1

#pragma unroll
    for (int os = 0; os < OSPLIT; ++os) {
        f32x4 acc[MT][2];
#pragma unroll
        for (int mt = 0; mt < MT; ++mt) {
            acc[mt][0] = {0.f, 0.f, 0.f, 0.f};
            acc[mt][1] = {0.f, 0.f, 0.f, 0.f};
        }

#pragma unroll
        for (int ks = 0; ks < KSPLIT; ++ks) {
            // ---- stage weight slice (96 out x 96 in) fp32 -> bf16 swizzled
            for (int k = tid; k < 96 * 24; k += 256) {
                int o = k / 24, c4 = (k - o * 24) * 4;
                float4 w4 = *reinterpret_cast<const float4*>(
                    &wgt[(size_t)(os * 96 + o) * CIN + ks * 96 + c4]);
                ushort4 pk = make_ushort4(f2bu(w4.x), f2bu(w4.y), f2bu(w4.z), f2bu(w4.w));
                *reinterpret_cast<ushort4*>(&s_w[swzo(o, c4, 96)]) = pk;
            }
            // ---- stage X slice [pos][chan], channel-pair u32 writes
            if (KSPLIT > 1 || os == 0) {
                for (int idx = tid; idx < 48 * 16; idx += 256) {
                    const int cp = idx >> 4;        // channel pair 0..47
                    const int pb = idx & 15;        // position block (8 pos)
                    const TI* gp = inb + (size_t)(ks * 96 + 2 * cp) * HW + hw0 + pb * 8;
                    unsigned short ua[8], ub[8];
                    if constexpr (__is_same(TI, float)) {
                        float4 a0 = *reinterpret_cast<const float4*>(gp);
                        float4 a1 = *reinterpret_cast<const float4*>(gp + 4);
                        float4 b0 = *reinterpret_cast<const float4*>(gp + HW);
                        float4 b1 = *reinterpret_cast<const float4*>(gp + HW + 4);
                        ua[0]=f2bu(a0.x); ua[1]=f2bu(a0.y); ua[2]=f2bu(a0.z); ua[3]=f2bu(a0.w);
                        ua[4]=f2bu(a1.x); ua[5]=f2bu(a1.y); ua[6]=f2bu(a1.z); ua[7]=f2bu(a1.w);
                        ub[0]=f2bu(b0.x); ub[1]=f2bu(b0.y); ub[2]=f2bu(b0.z); ub[3]=f2bu(b0.w);
                        ub[4]=f2bu(b1.x); ub[5]=f2bu(b1.y); ub[6]=f2bu(b1.z); ub[7]=f2bu(b1.w);
                    } else {
                        *reinterpret_cast<uint4*>(ua) = *reinterpret_cast<const uint4*>(gp);
                        *reinterpret_cast<uint4*>(ub) = *reinterpret_cast<const uint4*>(gp + HW);
                    }
#pragma unroll
                    for (int i = 0; i < 8; ++i) {
                        uint d = (uint)ua[i] | ((uint)ub[i] << 16);
                        *reinterpret_cast<uint*>(&s_x[swzo(pb * 8 + i, 2 * cp, 96)]) = d;
                    }
                }
            }
            __syncthreads();

            // ---- MFMA over this slice
#pragma unroll
            for (int kt = 0; kt < 3; ++kt) {
                const int col = kt * 32 + q * 8;
                union { unsigned short u[8]; bf16x8 v; } bf0, bf1;
                *reinterpret_cast<uint4*>(bf0.u) =
                    *reinterpret_cast<const uint4*>(&s_x[swzo(pl0, col, 96)]);
                *reinterpret_cast<uint4*>(bf1.u) =
                    *reinterpret_cast<const uint4*>(&s_x[swzo(pl1, col, 96)]);
#pragma unroll
                for (int mt = 0; mt < MT; ++mt) {
                    union { unsigned short u[8]; bf16x8 v; } fa;
                    *reinterpret_cast<uint4*>(fa.u) =
                        *reinterpret_cast<const uint4*>(&s_w[swzo(mt * 16 + n, col, 96)]);
                    acc[mt][0] = __builtin_amdgcn_mfma_f32_16x16x32_bf16(fa.v, bf0.v, acc[mt][0], 0, 0, 0);
                    acc[mt][1] = __builtin_amdgcn_mfma_f32_16x16x32_bf16(fa.v, bf1.v, acc[mt][1], 0, 0, 0);
                }
            }
            if (os + 1 < OSPLIT || ks + 1 < KSPLIT)
                __syncthreads();     // all slice reads done before next overwrite
        }

        // ---- epilogue for this out-slice (regs + s_b only; no LDS hazard)
        const int p0 = hw0 + pl0;
        const int p1 = hw0 + pl1;
        const size_t obase = (size_t)b * COUT * HW;
#pragma unroll
        for (int mt = 0; mt < MT; ++mt) {
#pragma unroll
            for (int nt = 0; nt < 2; ++nt) {
                const int p = (nt == 0) ? p0 : p1;
#pragma unroll
                for (int r = 0; r < 4; ++r) {
                    const int o = os * 96 + mt * 16 + q * 4 + r;
                    float v = acc[mt][nt][r] + s_b[o];
                    if constexpr (GELU) v = gelu_erf(v);
                    const size_t idx = obase + (size_t)o * HW + p;
                    if constexpr (HASRES) v += resid[idx];
                    if constexpr (__is_same(TOT, float)) out[idx] = v;
                    else                                 out[idx] = __float2bfloat16(v);
                }
            }
        }
    }
}

// ---------------- Kernel 3: experts, TRANSPOSED LDS stencil ----------------
// Layout: reads conflict-free (11w / 5w mod 32 bijective per half-wave);
// stage writes row-pair u32-packed, lane-mapped conflict-free (round 4).
#define XR     20
#define XPITCH 22      // 11 dwords (odd)
#define TPITCH 10      // 5 dwords (odd)
#define XCOLS  268
#define TCOLS  258

__global__ __launch_bounds__(256) void experts_kernel(
    const bf16* __restrict__ xn, const bf16* __restrict__ t0,
    const float* __restrict__ w0, const float* __restrict__ b0,
    const float* __restrict__ w1, const float* __restrict__ b1,
    const float* __restrict__ w2, const float* __restrict__ b2,
    const float* __restrict__ sw, const float* __restrict__ prompt,
    bf16* __restrict__ xa)
{
    __shared__ alignas(16) unsigned short sxT[XCOLS * XPITCH];
    __shared__ alignas(16) unsigned short stT[TCOLS * TPITCH];

    const int tid  = threadIdx.x;
    const int lane = tid & 63;
    const int wave = tid >> 6;
    const int bid = blockIdx.x;
    const int h0  = (bid & 31) * 8;
    const int bc  = bid >> 5;
    const int b   = bc / 96;
    const int c   = bc - b * 96;
    const size_t pbase = (size_t)bc * HW;

    const bf16* xp = xn + pbase;
    const bf16* tp = t0 + pbase;
    uint* sx32 = reinterpret_cast<uint*>(sxT);
    uint* st32 = reinterpret_cast<uint*>(stT);

    // ---- edge-pad zero fill (cols 0..5 & 262..267 of X; cols 0 & 257 of T)
    if (tid < 132) {                       // 12 cols x 11 dwords
        int cc = tid / 11, d = tid - cc * 11;
        int col = (cc < 6) ? cc : 256 + cc;
        sx32[col * 11 + d] = 0u;
    } else if (tid < 142) {                // 2 cols x 5 dwords
        int i = tid - 132;
        int col = (i < 5) ? 0 : 257;
        int d   = (i < 5) ? i : i - 5;
        st32[col * 5 + d] = 0u;
    }

    // ---- stage X: item = (rowpair rp, chunk ch); packed u32 writes
    {
        const int rp = (lane >> 2) & 7;
        const int ch = 8 * wave + (lane & 3) + ((lane >> 5) << 2);
        const int gh0 = h0 - 6 + 2 * rp, gh1 = gh0 + 1;
        union { uint4 q; unsigned short u[8]; } a, bb;
        a.q  = ((unsigned)gh0 < 256u) ? *reinterpret_cast<const uint4*>(xp + gh0 * WID + ch * 8)
                                      : make_uint4(0u, 0u, 0u, 0u);
        bb.q = ((unsigned)gh1 < 256u) ? *reinterpret_cast<const uint4*>(xp + gh1 * WID + ch * 8)
                                      : make_uint4(0u, 0u, 0u, 0u);
        const int base = 11 * (6 + 8 * ch) + rp;
#pragma unroll
        for (int j = 0; j < 8; ++j)
            sx32[base + 11 * j] = (uint)a.u[j] | ((uint)bb.u[j] << 16);
    }
    if (wave == 2) {   // X tail: rp 8..9
        const int rp = 8 + ((lane >> 2) & 1);
        const int ch = (lane & 3) + (((lane >> 3) & 7) << 2);
        const int gh0 = h0 - 6 + 2 * rp, gh1 = gh0 + 1;
        union { uint4 q; unsigned short u[8]; } a, bb;
        a.q  = ((unsigned)gh0 < 256u) ? *reinterpret_cast<const uint4*>(xp + gh0 * WID + ch * 8)
                                      : make_uint4(0u, 0u, 0u, 0u);
        bb.q = ((unsigned)gh1 < 256u) ? *reinterpret_cast<const uint4*>(xp + gh1 * WID + ch * 8)
                                      : make_uint4(0u, 0u, 0u, 0u);
        const int base = 11 * (6 + 8 * ch) + rp;
#pragma unroll
        for (int j = 0; j < 8; ++j)
            sx32[base + 11 * j] = (uint)a.u[j] | ((uint)bb.u[j] << 16);
    }
    if (wave < 2) {    // T main: rp 0..3
        const int rp = (lane >> 3) & 3;
        const int ch = 16 * wave + (lane & 7) + ((lane >> 5) << 3);
        const int gh0 = h0 - 1 + 2 * rp, gh1 = gh0 + 1;
        union { uint4 q; unsigned short u[8]; } a, bb;
        a.q  = ((unsigned)gh0 < 256u) ? *reinterpret_cast<const uint4*>(tp + gh0 * WID + ch * 8)
                                      : make_uint4(0u, 0u, 0u, 0u);
        bb.q = ((unsigned)gh1 < 256u) ? *reinterpret_cast<const uint4*>(tp + gh1 * WID + ch * 8)
                                      : make_uint4(0u, 0u, 0u, 0u);
        const int base = 5 * (1 + 8 * ch) + rp;
#pragma unroll
        for (int j = 0; j < 8; ++j)
            st32[base + 5 * j] = (uint)a.u[j] | ((uint)bb.u[j] << 16);
    }
    if (wave == 3 && lane < 32) {   // T tail: rp 4
        const int rp = 4;
        const int ch = lane;
        const int gh0 = h0 - 1 + 2 * rp, gh1 = gh0 + 1;
        union { uint4 q; unsigned short u[8]; } a, bb;
        a.q  = ((unsigned)gh0 < 256u) ? *reinterpret_cast<const uint4*>(tp + gh0 * WID + ch * 8)
                                      : make_uint4(0u, 0u, 0u, 0u);
        bb.q = ((unsigned)gh1 < 256u) ? *reinterpret_cast<const uint4*>(tp + gh1 * WID + ch * 8)
                                      : make_uint4(0u, 0u, 0u, 0u);
        const int base = 5 * (1 + 8 * ch) + rp;
#pragma unroll
        for (int j = 0; j < 8; ++j)
            st32[base + 5 * j] = (uint)a.u[j] | ((uint)bb.u[j] << 16);
    }

    // ---- per-channel weights (block-uniform -> scalar loads)
    float wk0[9], wk1[9], wk2[25];
#pragma unroll
    for (int i = 0; i < 9; ++i)  wk0[i] = w0[c * 9 + i];
#pragma unroll
    for (int i = 0; i < 9; ++i)  wk1[i] = w1[c * 9 + i];
#pragma unroll
    for (int i = 0; i < 25; ++i) wk2[i] = w2[c * 25 + i];
    const float bb0 = b0[c], bb1 = b1[c], bb2 = b2[c];
    const float s0 = sw[b * 3 + 0], s1 = sw[b * 3 + 1], s2 = sw[b * 3 + 2];
    const float pr = 1.f + prompt[b * 96 + c];

    __syncthreads();

    // ---- compute: thread = column w, 8 vertical outputs
    const int w = tid;
    float acc0[8], acc1[8], acc2[8];
#pragma unroll
    for (int r = 0; r < 8; ++r) { acc0[r] = bb0; acc1[r] = bb1; acc2[r] = bb2; }

    const unsigned short* bx = &sxT[w * XPITCH];  // = LDS col of global col (w-6)
    const unsigned short* bt = &stT[w * TPITCH];  // = LDS col of global col (w-1)

    // e2: 5x5 dil 3; e1 center column folded into kw=2 strip
#pragma unroll
    for (int kw = 0; kw < 5; ++kw) {
        float cv[20];
#pragma unroll
        for (int j = 0; j < 10; ++j) {
            unsigned u = *reinterpret_cast<const unsigned*>(&bx[kw * 3 * XPITCH + 2 * j]);
            cv[2 * j]     = lo2f(u);
            cv[2 * j + 1] = hi2f(u);
        }
#pragma unroll
        for (int kh = 0; kh < 5; ++kh) {
            const float wv = wk2[kh * 5 + kw];
#pragma unroll
            for (int r = 0; r < 8; ++r) acc2[r] += wv * cv[r + 3 * kh];
        }
        if (kw == 2) {
#pragma unroll
            for (int kh = 0; kh < 3; ++kh) {
                const float wv = wk1[kh * 3 + 1];
#pragma unroll
                for (int r = 0; r < 8; ++r) acc1[r] += wv * cv[r + 2 * kh + 4];
            }
        }
    }
    // e1: 3x3 dil 2, kw = 0 and 2
#pragma unroll
    for (int kwh = 0; kwh < 2; ++kwh) {
        const int kw = kwh * 2;
        float cv[12];
#pragma unroll
        for (int j = 0; j < 6; ++j) {
            unsigned u = *reinterpret_cast<const unsigned*>(&bx[(4 + 2 * kw) * XPITCH + 4 + 2 * j]);
            cv[2 * j]     = lo2f(u);
            cv[2 * j + 1] = hi2f(u);
        }
#pragma unroll
        for (int kh = 0; kh < 3; ++kh) {
            const float wv = wk1[kh * 3 + kw];
#pragma unroll
            for (int r = 0; r < 8; ++r) acc1[r] += wv * cv[r + 2 * kh];
        }
    }
    // e0: 3x3 dil 1 on t0
#pragma unroll
    for (int kw = 0; kw < 3; ++kw) {
        float cv[10];
#pragma unroll
        for (int j = 0; j < 5; ++j) {
            unsigned u = *reinterpret_cast<const unsigned*>(&bt[kw * TPITCH + 2 * j]);
            cv[2 * j]     = lo2f(u);
            cv[2 * j + 1] = hi2f(u);
        }
#pragma unroll
        for (int kh = 0; kh < 3; ++kh) {
            const float wv = wk0[kh * 3 + kw];
#pragma unroll
            for (int r = 0; r < 8; ++r) acc0[r] += wv * cv[r + kh];
        }
    }

    // ---- combine + store
    bf16* op = xa + pbase + (size_t)h0 * WID + w;
#pragma unroll
    for (int r = 0; r < 8; ++r) {
        float v = (s0 * acc0[r] + s1 * acc1[r] + s2 * acc2[r]) * pr;
        op[r * WID] = __float2bfloat16(v);
    }
}

// ---------------- launch ----------------
extern "C" void kernel_launch(void* const* d_in, const int* in_sizes, int n_in,
                              void* d_out, int out_size, void* d_ws, size_t ws_size,
                              hipStream_t stream)
{
    const float* x       = (const float*)d_in[0];
    const float* prompt  = (const float*)d_in[1];
    const float* sw      = (const float*)d_in[2];
    const float* ln_w    = (const float*)d_in[3];
    const float* ln_b    = (const float*)d_in[4];
    const float* e0_pw_w = (const float*)d_in[5];
    const float* e0_pw_b = (const float*)d_in[6];
    const float* e0_dw_w = (const float*)d_in[7];
    const float* e0_dw_b = (const float*)d_in[8];
    const float* e1_dw_w = (const float*)d_in[9];
    const float* e1_dw_b = (const float*)d_in[10];
    const float* e2_dw_w = (const float*)d_in[11];
    const float* e2_dw_b = (const float*)d_in[12];
    const float* proj_w  = (const float*)d_in[13];
    const float* proj_b  = (const float*)d_in[14];
    const float* ffn1_w  = (const float*)d_in[15];
    const float* ffn1_b  = (const float*)d_in[16];
    const float* ffn2_w  = (const float*)d_in[17];
    const float* ffn2_b  = (const float*)d_in[18];

    float* out = (float*)d_out;                 // x1 lives here fp32 between k4..k6
    bf16*  ws  = (bf16*)d_ws;
    bf16*  A   = ws;                 // xn  bf16 (48 MB)
    bf16*  Bt  = ws + S_ELEMS;       // t0  bf16 (48 MB)
    bf16*  Cx  = ws + 2 * S_ELEMS;   // xa  bf16 (48 MB)  -> peak ws = 144 MB
    bf16*  E   = ws;                 // h (192 ch) bf16 (96 MB), reuses A+Bt once dead

    // 1) xn = LayerNorm_c(x)
    ln_kernel<<<512, 256, 0, stream>>>(x, ln_w, ln_b, A);
    // 2) t0 = conv1x1(xn, e0_pw)
    conv1x1_mfma<bf16, bf16, 96, 96, false, false>
        <<<2048, 256, 0, stream>>>(A, e0_pw_w, e0_pw_b, nullptr, Bt);
    // 3) xa = (s0*dw3(t0) + s1*dw3d2(xn) + s2*dw5d3(xn)) * (1+prompt)
    experts_kernel<<<12288, 256, 0, stream>>>(A, Bt, e0_dw_w, e0_dw_b, e1_dw_w, e1_dw_b,
                                              e2_dw_w, e2_dw_b, sw, prompt, Cx);
    // 4) x1 = x + conv1x1(xa, proj)  -> d_out (fp32)
    conv1x1_mfma<bf16, float, 96, 96, false, true>
        <<<2048, 256, 0, stream>>>(Cx, proj_w, proj_b, x, out);
    // 5) h = gelu(conv1x1(x1, ffn1)) -> E (bf16)
    conv1x1_mfma<float, bf16, 96, 192, true, false>
        <<<2048, 256, 0, stream>>>(out, ffn1_w, ffn1_b, nullptr, E);
    // 6) out = x1 + conv1x1(h, ffn2) -> d_out (in-place, per-thread same-address RMW)
    conv1x1_mfma<bf16, float, 192, 96, false, true>
        <<<2048, 256, 0, stream>>>(E, ffn2_w, ffn2_b, out, out);
}